// Round 5
// baseline (459.178 us; speedup 1.0000x reference)
//
#include <hip/hip_runtime.h>
#include <math.h>

#define NB 32
#define NT 1024
#define ND 256
#define NROWS (NB*NT)
#define MAXE 64
#define AST 272   // LDS row stride (shorts) for 256-wide rows: 544 B = 8-bank row step

typedef __attribute__((ext_vector_type(8))) short bf16x8;
typedef __attribute__((ext_vector_type(4))) float f32x4;
typedef unsigned short ushort_t;
typedef unsigned long long u64;

__device__ inline ushort_t f2bf_rn(float f){
  unsigned u = __float_as_uint(f);
  unsigned r = u + 0x7fffu + ((u >> 16) & 1u);
  return (ushort_t)(r >> 16);
}
__device__ inline float bf2f(ushort_t h){
  return __uint_as_float(((unsigned)h) << 16);
}
__device__ inline void ceswap(u64 &a, u64 &b){
  u64 mx = a > b ? a : b;
  u64 mn = a > b ? b : a;
  a = mx; b = mn;
}
__device__ inline u64 umax64(u64 a, u64 b){ return a > b ? a : b; }

// ---------------- K1: row L2-normalize + bf16 split (xh + xl = xn) ----------
__global__ __launch_bounds__(256) void k_norm(const float* __restrict__ x,
                                              float* __restrict__ xn,
                                              ushort_t* __restrict__ xh,
                                              ushort_t* __restrict__ xl){
  int row = blockIdx.x;
  int t = threadIdx.x;
  size_t base = (size_t)row*ND;
  float v = x[base + t];
  float ss = v*v;
  #pragma unroll
  for (int off=32; off; off>>=1) ss += __shfl_xor(ss, off);
  __shared__ float sred[4];
  if ((t & 63) == 0) sred[t>>6] = ss;
  __syncthreads();
  float tot = sred[0] + sred[1] + sred[2] + sred[3];
  float nrm = fmaxf(sqrtf(tot), 1e-12f);
  float res = v / nrm;
  xn[base + t] = res;
  ushort_t hb = f2bf_rn(res);
  float lres = res - bf2f(hb);
  xh[base + t] = hb;
  xl[base + t] = f2bf_rn(lres);
}

// ---------------- Kw: split W into bf16 high/low streams --------------------
__global__ __launch_bounds__(256) void k_wsplit(const float* __restrict__ W0,
                                                const float* __restrict__ W1,
                                                ushort_t* __restrict__ Wh0, ushort_t* __restrict__ Wl0,
                                                ushort_t* __restrict__ Wh1, ushort_t* __restrict__ Wl1){
  int idx = blockIdx.x*256 + threadIdx.x;    // 65536
  float w0 = W0[idx]; ushort_t h0 = f2bf_rn(w0);
  Wh0[idx] = h0; Wl0[idx] = f2bf_rn(w0 - bf2f(h0));
  float w1 = W1[idx]; ushort_t h1 = f2bf_rn(w1);
  Wh1[idx] = h1; Wl1[idx] = f2bf_rn(w1 - bf2f(h1));
}

// ---------------- K2: MFMA sim GEMM (bf16-split, 3 passes), S out bf16 ------
__global__ __launch_bounds__(256) void k_sim(const ushort_t* __restrict__ xh,
                                             const ushort_t* __restrict__ xl,
                                             ushort_t* __restrict__ S,
                                             int bat0){
  __shared__ __align__(16) ushort_t lds[2*128*80];   // 40 KB
  ushort_t* As  = lds;
  ushort_t* Bsm = lds + 128*80;

  int blk = blockIdx.x;
  int b_local = blk >> 6;
  int b = bat0 + b_local;
  int tt = blk & 63;
  int ti = tt >> 3, tj = tt & 7;
  int i0 = ti*128, j0 = tj*128;

  int t = threadIdx.x;
  int lane = t & 63, wave = t >> 6;
  int wy = wave >> 1, wx = wave & 1;
  int c = lane & 15, q = lane >> 4;

  f32x4 acc[4][4];
  #pragma unroll
  for (int bi=0;bi<4;bi++)
    #pragma unroll
    for (int bj=0;bj<4;bj++) acc[bi][bj] = {0.f,0.f,0.f,0.f};

  size_t rowbA = (size_t)(b*NT + i0);
  size_t rowbB = (size_t)(b*NT + j0);

  for (int p=0; p<3; p++){
    const ushort_t* Ags = (p==1) ? xl : xh;
    const ushort_t* Bgs = (p==2) ? xl : xh;
    const ushort_t* Ag = Ags + rowbA*ND;
    const ushort_t* Bg = Bgs + rowbB*ND;
    for (int kc=0; kc<4; kc++){
      __syncthreads();
      { // stage A and B chunks: 128 rows x 64 bf16 each
        int r0 = t >> 3, seg = t & 7;
        #pragma unroll
        for (int g=0; g<4; g++){
          int r = r0 + g*32;
          float4 va = *(const float4*)&Ag[(size_t)r*ND + kc*64 + seg*8];
          *(float4*)&As[r*80 + seg*8] = va;
          float4 vb = *(const float4*)&Bg[(size_t)r*ND + kc*64 + seg*8];
          *(float4*)&Bsm[r*80 + seg*8] = vb;
        }
      }
      __syncthreads();
      #pragma unroll
      for (int ks=0; ks<2; ks++){
        bf16x8 af[4], bfr[4];
        #pragma unroll
        for (int bi=0;bi<4;bi++)
          af[bi] = *(const bf16x8*)&As[(wy*64 + bi*16 + c)*80 + ks*32 + q*8];
        #pragma unroll
        for (int bj=0;bj<4;bj++)
          bfr[bj] = *(const bf16x8*)&Bsm[(wx*64 + bj*16 + c)*80 + ks*32 + q*8];
        #pragma unroll
        for (int bi=0;bi<4;bi++)
          #pragma unroll
          for (int bj=0;bj<4;bj++)
            acc[bi][bj] = __builtin_amdgcn_mfma_f32_16x16x32_bf16(af[bi], bfr[bj], acc[bi][bj], 0, 0, 0);
      }
    }
  }

  // epilogue: store bf16 S tile. C/D layout: col=lane&15, row=q*4+reg.
  size_t srow0 = (size_t)b_local*NT + i0 + wy*64;
  int col0 = j0 + wx*64;
  #pragma unroll
  for (int bi=0;bi<4;bi++){
    #pragma unroll
    for (int reg=0;reg<4;reg++){
      ushort_t* dst = S + (srow0 + bi*16 + q*4 + reg)*NT + col0;
      #pragma unroll
      for (int bj=0;bj<4;bj++)
        dst[bj*16 + c] = f2bf_rn(acc[bi][bj][reg]);
    }
  }
}

// ---------------- K3: stream S rows -> exact approx-top-4 indices per row ---
__global__ __launch_bounds__(256) void k_top8(const ushort_t* __restrict__ S,
                                              int4* __restrict__ cand4,
                                              int rowbase){
  int row = blockIdx.x*4 + (threadIdx.x >> 6);   // local row in half
  int lane = threadIdx.x & 63;
  int i = row & 1023;
  const ushort_t* Sr = S + (size_t)row*NT;
  u64 e0 = 0, e1 = 0;
  #pragma unroll
  for (int seg=0; seg<4; seg++){
    int col = seg*256 + lane*4;
    u64 v4 = *(const u64*)&Sr[col];   // 4 bf16
    #pragma unroll
    for (int m=0;m<4;m++){
      unsigned u = (unsigned)((v4 >> (16*m)) & 0xffffu) << 16;
      unsigned key = u ^ ((unsigned)((int)u >> 31) | 0x80000000u);
      int j = col + m;
      u64 e = ((u64)key << 32) | (unsigned)j;
      if (j == i) e = 0;              // diag suppressed
      u64 mn = e0 > e ? e : e0;
      e0 = e0 > e ? e0 : e;
      e1 = e1 > mn ? e1 : mn;
    }
  }
  u64 L0 = e0, L1 = e1, L2 = 0, L3 = 0;
  #pragma unroll
  for (int st=1; st<64; st<<=1){
    u64 R0 = __shfl_xor(L0, st), R1 = __shfl_xor(L1, st);
    u64 R2 = __shfl_xor(L2, st), R3 = __shfl_xor(L3, st);
    u64 m0 = umax64(L0, R3), m1 = umax64(L1, R2);
    u64 m2 = umax64(L2, R1), m3 = umax64(L3, R0);
    ceswap(m0, m2); ceswap(m1, m3); ceswap(m0, m1); ceswap(m2, m3);
    L0 = m0; L1 = m1; L2 = m2; L3 = m3;
  }
  if (lane == 0)
    cand4[rowbase + row] = make_int4((int)(unsigned)L0, (int)(unsigned)L1,
                                     (int)(unsigned)L2, (int)(unsigned)L3);
}

// ---------------- K3b: fp64-exact refine of 4 candidates -> top-2 -----------
__global__ __launch_bounds__(64) void k_refine4(const float* __restrict__ xn,
                                                const int4* __restrict__ cand4,
                                                int2* __restrict__ top2){
  int row = blockIdx.x; int b = row >> 10, i = row & 1023;
  int l = threadIdx.x;
  const float* Xb = xn + (size_t)b*NT*ND;
  float4 xi = *(const float4*)&Xb[(size_t)i*ND + l*4];
  int4 cd = cand4[row];
  int cands[4] = {cd.x, cd.y, cd.z, cd.w};
  double bv1=-1e30, bv2=-1e30; int bi1=0x7fffffff, bi2=0x7fffffff;
  #pragma unroll
  for (int cq=0;cq<4;cq++){
    int j = cands[cq];
    float4 xj = *(const float4*)&Xb[(size_t)j*ND + l*4];
    double p = (double)xi.x*xj.x + (double)xi.y*xj.y
             + (double)xi.z*xj.z + (double)xi.w*xj.w;
    #pragma unroll
    for (int off=32; off; off>>=1) p += __shfl_xor(p, off);
    if (p > bv1 || (p == bv1 && j < bi1)) { bv2=bv1; bi2=bi1; bv1=p; bi1=j; }
    else if (p > bv2 || (p == bv2 && j < bi2)) { bv2=p; bi2=j; }
  }
  if (l == 0) top2[row] = make_int2(bi1, bi2);
}

// ---------------- K4: scatter symmetric ext edges into bitmask --------------
__global__ __launch_bounds__(256) void k_scatter(const int2* __restrict__ top2,
                                                 unsigned* __restrict__ ext){
  int row = blockIdx.x*256 + threadIdx.x;
  int b = row >> 10, i = row & 1023;
  int2 tp = top2[row];
  unsigned* eb = ext + (size_t)b*NT*32;
  int j1 = tp.x, j2 = tp.y;
  atomicOr(&eb[(size_t)i*32 + (j1>>5)], 1u << (j1&31));
  atomicOr(&eb[(size_t)j1*32 + (i>>5)], 1u << (i&31));
  atomicOr(&eb[(size_t)i*32 + (j2>>5)], 1u << (j2&31));
  atomicOr(&eb[(size_t)j2*32 + (i>>5)], 1u << (i&31));
}

// ---------------- K5: enumerate edge union, recompute sim values, row sums --
__global__ __launch_bounds__(64) void k_edges(const float* __restrict__ xn,
                                              const unsigned* __restrict__ ext,
                                              int* __restrict__ eidx,
                                              float* __restrict__ eval_,
                                              float* __restrict__ rs,
                                              int* __restrict__ ecnt){
  int row = blockIdx.x; int b = row >> 10, i = row & 1023;
  int l = threadIdx.x;
  const float* Xb = xn + (size_t)b*NT*ND;
  float4 xi = *(const float4*)&Xb[(size_t)i*ND + l*4];
  unsigned word = 0;
  if (l < 32){
    word = ext[((size_t)b*NT + i)*32 + l];
    int js[3] = {i-1, i, i+1};
    #pragma unroll
    for (int qd=0;qd<3;qd++){
      int j = js[qd];
      if (j >= 0 && j < NT && (j>>5) == l) word |= (1u << (j&31));
    }
  }
  float rsum = 0.f; int cnt = 0;
  for (int w=0; w<32; w++){
    unsigned bits = __shfl(word, w);
    while (bits){
      int bit = __ffs(bits) - 1;
      bits &= bits - 1;
      int j = w*32 + bit;
      float4 xj = *(const float4*)&Xb[(size_t)j*ND + l*4];
      float p = xi.x*xj.x + xi.y*xj.y + xi.z*xj.z + xi.w*xj.w;
      #pragma unroll
      for (int off=32; off; off>>=1) p += __shfl_xor(p, off);
      float v = p + ((j==i) ? 1.0f : 0.0f);
      if (l == 0 && cnt < MAXE){
        eidx[(size_t)row*MAXE + cnt] = j;
        eval_[(size_t)row*MAXE + cnt] = v;
      }
      rsum += v; cnt++;
    }
  }
  if (l == 0){ rs[row] = rsum + 1e-6f; ecnt[row] = (cnt < MAXE) ? cnt : MAXE; }
}

// ---------------- K6: sparse aggregation, output split bf16 (hh + hl) -------
__global__ __launch_bounds__(256) void k_spmm(const float* __restrict__ hin,
                                              const int* __restrict__ eidx,
                                              const float* __restrict__ eval_,
                                              const float* __restrict__ rs,
                                              const int* __restrict__ ecnt,
                                              ushort_t* __restrict__ hh,
                                              ushort_t* __restrict__ hl){
  int row = blockIdx.x; int b = row >> 10;
  int t = threadIdx.x;
  float rsi = rs[row];
  int n = ecnt[row];
  float acc = 0.f;
  for (int e=0;e<n;e++){
    int j   = eidx[(size_t)row*MAXE + e];
    float v = eval_[(size_t)row*MAXE + e];
    float w = v / sqrtf(rsi * rs[b*NT + j]);
    acc += w * hin[((size_t)b*NT + j)*ND + t];
  }
  ushort_t hb = f2bf_rn(acc);
  hh[(size_t)row*ND + t] = hb;
  hl[(size_t)row*ND + t] = f2bf_rn(acc - bf2f(hb));
}

// ---------------- K7: MFMA dense h@W^T + bias + elu + LayerNorm -------------
// 64 rows x 256 cols per block, 4 waves (wave w -> cols 64w..64w+63).
// Entire split-A (64x256 h + l) staged in LDS ONCE (stride AST=272 -> 8-bank
// row step, the measured-conflict-free pattern); K-loop has NO barriers, W
// fragments stream from L2-hot global (256 KB total, reused by all blocks)
// with full compiler prefetch freedom. fp32 epilogue, 2-pass LN.
__global__ __launch_bounds__(256) void k_dense2(const ushort_t* __restrict__ hh,
                                                const ushort_t* __restrict__ hl,
                                                const ushort_t* __restrict__ Wh,
                                                const ushort_t* __restrict__ Wl,
                                                const float* __restrict__ bias,
                                                const float* __restrict__ gam,
                                                const float* __restrict__ bet,
                                                float* __restrict__ out){
  __shared__ __align__(16) ushort_t Ah[64*AST];
  __shared__ __align__(16) ushort_t Al[64*AST];
  __shared__ float sums[64*4];
  __shared__ float sqs[64*4];
  __shared__ float muA[64];
  __shared__ float rsA[64];

  int t = threadIdx.x;
  int lane = t & 63, wave = t >> 6;
  int c = lane & 15, q = lane >> 4;
  size_t row0 = (size_t)blockIdx.x * 64;

  { // stage full split-A: 64 rows x 256 shorts per stream, coalesced 16B/lane
    #pragma unroll
    for (int it=0; it<8; it++){
      int r = it*8 + (t>>5), cs = (t&31)*8;
      *(float4*)&Ah[r*AST + cs] = *(const float4*)&hh[(row0+r)*ND + cs];
      *(float4*)&Al[r*AST + cs] = *(const float4*)&hl[(row0+r)*ND + cs];
    }
  }
  __syncthreads();   // the ONLY barrier before the epilogue

  f32x4 acc[4][4];   // [bi (row group)][bj (col group)]
  #pragma unroll
  for (int bi=0;bi<4;bi++)
    #pragma unroll
    for (int bj=0;bj<4;bj++) acc[bi][bj] = {0.f,0.f,0.f,0.f};

  #pragma unroll 1
  for (int kc=0; kc<4; kc++){
    #pragma unroll
    for (int ks=0; ks<2; ks++){
      int ko = kc*64 + ks*32 + q*8;
      bf16x8 ah[4], al[4], wh[4], wl[4];
      #pragma unroll
      for (int bj=0;bj<4;bj++){
        size_t wo = (size_t)(wave*64 + bj*16 + c)*ND + ko;
        wh[bj] = *(const bf16x8*)&Wh[wo];
        wl[bj] = *(const bf16x8*)&Wl[wo];
      }
      #pragma unroll
      for (int bi=0;bi<4;bi++){
        ah[bi] = *(const bf16x8*)&Ah[(bi*16+c)*AST + ko];
        al[bi] = *(const bf16x8*)&Al[(bi*16+c)*AST + ko];
      }
      #pragma unroll
      for (int bi=0;bi<4;bi++)
        #pragma unroll
        for (int bj=0;bj<4;bj++){
          acc[bi][bj] = __builtin_amdgcn_mfma_f32_16x16x32_bf16(ah[bi], wh[bj], acc[bi][bj], 0, 0, 0);
          acc[bi][bj] = __builtin_amdgcn_mfma_f32_16x16x32_bf16(al[bi], wh[bj], acc[bi][bj], 0, 0, 0);
          acc[bi][bj] = __builtin_amdgcn_mfma_f32_16x16x32_bf16(ah[bi], wl[bj], acc[bi][bj], 0, 0, 0);
        }
    }
  }

  // bias + elu (in acc regs)
  float bv[4], gv[4], tv[4];
  #pragma unroll
  for (int bj=0;bj<4;bj++){
    int col = wave*64 + bj*16 + c;
    bv[bj] = bias[col]; gv[bj] = gam[col]; tv[bj] = bet[col];
  }
  #pragma unroll
  for (int bi=0;bi<4;bi++)
    #pragma unroll
    for (int bj=0;bj<4;bj++)
      #pragma unroll
      for (int reg=0;reg<4;reg++){
        float v = acc[bi][bj][reg] + bv[bj];
        acc[bi][bj][reg] = (v > 0.f) ? v : expm1f(v);
      }

  // LN pass 1: mean. C/D layout: row = bi*16 + q*4 + reg, col-lane = c.
  #pragma unroll
  for (int bi=0;bi<4;bi++)
    #pragma unroll
    for (int reg=0;reg<4;reg++){
      float s = acc[bi][0][reg] + acc[bi][1][reg] + acc[bi][2][reg] + acc[bi][3][reg];
      #pragma unroll
      for (int st=1; st<16; st<<=1) s += __shfl_xor(s, st);
      if (c == 0) sums[(bi*16 + q*4 + reg)*4 + wave] = s;
    }
  __syncthreads();
  if (t < 64){
    float s = sums[t*4] + sums[t*4+1] + sums[t*4+2] + sums[t*4+3];
    muA[t] = s * (1.0f/ND);
  }
  __syncthreads();
  // LN pass 2: variance
  #pragma unroll
  for (int bi=0;bi<4;bi++)
    #pragma unroll
    for (int reg=0;reg<4;reg++){
      float mu = muA[bi*16 + q*4 + reg];
      float ss = 0.f;
      #pragma unroll
      for (int bj=0;bj<4;bj++){ float d = acc[bi][bj][reg] - mu; ss += d*d; }
      #pragma unroll
      for (int st=1; st<16; st<<=1) ss += __shfl_xor(ss, st);
      if (c == 0) sqs[(bi*16 + q*4 + reg)*4 + wave] = ss;
    }
  __syncthreads();
  if (t < 64){
    float ss = sqs[t*4] + sqs[t*4+1] + sqs[t*4+2] + sqs[t*4+3];
    rsA[t] = rsqrtf(ss * (1.0f/ND) + 1e-5f);
  }
  __syncthreads();
  // affine + store
  #pragma unroll
  for (int bi=0;bi<4;bi++)
    #pragma unroll
    for (int reg=0;reg<4;reg++){
      int row = bi*16 + q*4 + reg;
      float mu = muA[row], rst = rsA[row];
      #pragma unroll
      for (int bj=0;bj<4;bj++){
        float val = (acc[bi][bj][reg] - mu) * rst * gv[bj] + tv[bj];
        out[(row0 + row)*ND + wave*64 + bj*16 + c] = val;
      }
    }
}

// ---------------- host launch ----------------
extern "C" void kernel_launch(void* const* d_in, const int* in_sizes, int n_in,
                              void* d_out, int out_size, void* d_ws, size_t ws_size,
                              hipStream_t stream) {
  (void)in_sizes; (void)n_in; (void)out_size; (void)ws_size;
  const float* x   = (const float*)d_in[0];
  const float* W0  = (const float*)d_in[2];
  const float* b0  = (const float*)d_in[3];
  const float* g0  = (const float*)d_in[4];
  const float* be0 = (const float*)d_in[5];
  const float* W1  = (const float*)d_in[6];
  const float* b1  = (const float*)d_in[7];
  const float* g1  = (const float*)d_in[8];
  const float* be1 = (const float*)d_in[9];
  float* out = (float*)d_out;

  char* wsb = (char*)d_ws;
  // Zone A: xn (permanent)                        [0, 32 MB)
  float* xn = (float*)wsb;
  // Zone B: xh+xl (k_norm -> k_sim), then hh+hl (k_spmm -> k_dense2) [32,64 MB)
  ushort_t* xh = (ushort_t*)(wsb + (size_t)32*1024*1024);
  ushort_t* xl = (ushort_t*)(wsb + (size_t)48*1024*1024);
  ushort_t* hh = xh;   // lifetime-disjoint: xh/xl dead after k_sim
  ushort_t* hl = xl;
  // Zone C: S half (k_sim -> k_top8), then ext/eidx/eval/rs/ecnt  [64, 97.6 MB)
  char* zc = wsb + (size_t)64*1024*1024;
  ushort_t* S = (ushort_t*)zc;                      // 33.55 MB
  unsigned* ext   = (unsigned*)zc;                                  // 4 MB
  int*      eidx  = (int*)(zc + (size_t)4*1024*1024);               // 8 MB
  float*    eval_ = (float*)(zc + (size_t)12*1024*1024);            // 8 MB
  float*    rs    = (float*)(zc + (size_t)20*1024*1024);            // 128 KB
  int*      ecnt  = (int*)(zc + (size_t)21*1024*1024);              // 128 KB
  // Zone D: small persistents                     [98 MB, ...)
  char* zd = wsb + (size_t)98*1024*1024;
  int4* cand4 = (int4*)zd;                            // 512 KB
  int2* top2  = (int2*)(zd + (size_t)512*1024);       // 256 KB
  ushort_t* Wh0 = (ushort_t*)(zd + (size_t)1024*1024);
  ushort_t* Wl0 = Wh0 + 65536;
  ushort_t* Wh1 = Wl0 + 65536;
  ushort_t* Wl1 = Wh1 + 65536;

  k_wsplit<<<256, 256, 0, stream>>>(W0, W1, Wh0, Wl0, Wh1, Wl1);
  k_norm<<<NROWS, 256, 0, stream>>>(x, xn, xh, xl);
  for (int h=0; h<2; h++){
    int bat0 = h*16;
    k_sim<<<1024, 256, 0, stream>>>(xh, xl, S, bat0);
    k_top8<<<4096, 256, 0, stream>>>(S, cand4, bat0*NT);
  }
  k_refine4<<<NROWS, 64, 0, stream>>>(xn, cand4, top2);
  hipMemsetAsync(ext, 0, (size_t)NROWS*32*4, stream);
  k_scatter<<<NROWS/256, 256, 0, stream>>>(top2, ext);
  k_edges<<<NROWS, 64, 0, stream>>>(xn, ext, eidx, eval_, rs, ecnt);
  // layer 1
  k_spmm<<<NROWS, 256, 0, stream>>>(x, eidx, eval_, rs, ecnt, hh, hl);
  k_dense2<<<NROWS/64, 256, 0, stream>>>(hh, hl, Wh0, Wl0, b0, g0, be0, out);
  // layer 2
  k_spmm<<<NROWS, 256, 0, stream>>>(out, eidx, eval_, rs, ecnt, hh, hl);
  k_dense2<<<NROWS/64, 256, 0, stream>>>(hh, hl, Wh1, Wl1, b1, g1, be1, out);
}